// Round 1
// baseline (642.511 us; speedup 1.0000x reference)
//
#include <hip/hip_runtime.h>
#include <math.h>

#define DI 1536
#define DM 768
#define NSTATE 16
#define DTRANK 48
#define LSEQ 1024
#define NBATCH 2
#define MROWS (NBATCH*LSEQ)   // 2048
#define NXR 3072              // 2*DI

// ---------------- f32 tiled GEMM: C[M,N] = A[M,K] @ B[K,N] ----------------
// 64x64 tile, BK=16, 256 threads, 4x4 per thread.
__global__ __launch_bounds__(256) void gemm_f32_64x64(
    const float* __restrict__ A, const float* __restrict__ B,
    float* __restrict__ C, int M, int N, int K)
{
  __shared__ float As[16][68];   // [k][m], stride 68 -> 16B aligned b128 reads
  __shared__ float Bs[16][64];   // [k][n]
  const int tid = threadIdx.x;
  const int tx = tid & 15, ty = tid >> 4;
  const int m0 = blockIdx.y * 64, n0 = blockIdx.x * 64;
  float acc[4][4] = {};
  for (int k0 = 0; k0 < K; k0 += 16) {
    #pragma unroll
    for (int i = 0; i < 4; ++i) {
      int r = ty + i * 16;
      As[tx][r] = A[(long)(m0 + r) * K + k0 + tx];
    }
    {
      int c = tid & 63, r0 = tid >> 6;
      #pragma unroll
      for (int i = 0; i < 4; ++i) {
        int r = r0 + i * 4;
        Bs[r][c] = B[(long)(k0 + r) * N + n0 + c];
      }
    }
    __syncthreads();
    #pragma unroll
    for (int k = 0; k < 16; ++k) {
      float av[4], bv[4];
      #pragma unroll
      for (int i = 0; i < 4; ++i) av[i] = As[k][ty * 4 + i];
      #pragma unroll
      for (int j = 0; j < 4; ++j) bv[j] = Bs[k][tx * 4 + j];
      #pragma unroll
      for (int i = 0; i < 4; ++i)
        #pragma unroll
        for (int j = 0; j < 4; ++j)
          acc[i][j] = fmaf(av[i], bv[j], acc[i][j]);
    }
    __syncthreads();
  }
  #pragma unroll
  for (int i = 0; i < 4; ++i) {
    int m = m0 + ty * 4 + i;
    #pragma unroll
    for (int j = 0; j < 4; ++j)
      C[(long)m * N + n0 + tx * 4 + j] = acc[i][j];
  }
}

// ---------------- depthwise causal conv(4) + bias + SiLU ----------------
// xi part lives in xr[m*3072 + c], c < 1536
__global__ __launch_bounds__(256) void conv_silu_kernel(
    const float* __restrict__ xr,
    const float* __restrict__ conv_w,
    const float* __restrict__ conv_b,
    float* __restrict__ u)
{
  int idx = blockIdx.x * 256 + threadIdx.x;
  if (idx >= MROWS * DI) return;
  int c = idx % DI;
  int bm = idx / DI;
  int t = bm % LSEQ;
  int b = bm / LSEQ;
  float w0 = conv_w[c * 4 + 0], w1 = conv_w[c * 4 + 1];
  float w2 = conv_w[c * 4 + 2], w3 = conv_w[c * 4 + 3];
  const float* xc = xr + (long)b * LSEQ * NXR + c;
  float acc = conv_b[c];
  if (t >= 3) acc = fmaf(xc[(long)(t - 3) * NXR], w0, acc);
  if (t >= 2) acc = fmaf(xc[(long)(t - 2) * NXR], w1, acc);
  if (t >= 1) acc = fmaf(xc[(long)(t - 1) * NXR], w2, acc);
  acc = fmaf(xc[(long)t * NXR], w3, acc);
  u[idx] = acc / (1.f + __expf(-acc));   // silu
}

// ---------------- x_dbl = u @ W_x  (2048 x 1536 @ 1536 x 80) ----------------
__global__ __launch_bounds__(128) void xdbl_kernel(
    const float* __restrict__ u,
    const float* __restrict__ W_x,
    float* __restrict__ xdbl)
{
  int m = blockIdx.x;
  int j = threadIdx.x;
  const float* ur = u + (long)m * DI;
  if (j < 80) {
    float acc = 0.f;
    #pragma unroll 4
    for (int k = 0; k < DI; ++k)
      acc = fmaf(ur[k], W_x[(long)k * 80 + j], acc);
    xdbl[(long)m * 80 + j] = acc;
  }
}

// ---------------- delta = softplus(xdbl[:, :48] @ W_dt + b_dt) ----------------
__global__ __launch_bounds__(256) void delta_kernel(
    const float* __restrict__ xdbl,
    const float* __restrict__ W_dt,
    const float* __restrict__ b_dt,
    float* __restrict__ delta)
{
  __shared__ float sx[DTRANK];
  int m = blockIdx.y;
  int c = blockIdx.x * 256 + threadIdx.x;
  if (threadIdx.x < DTRANK) sx[threadIdx.x] = xdbl[(long)m * 80 + threadIdx.x];
  __syncthreads();
  float acc = b_dt[c];
  #pragma unroll 8
  for (int r = 0; r < DTRANK; ++r)
    acc = fmaf(sx[r], W_dt[(long)r * DI + c], acc);
  float sp = (acc > 20.f) ? acc : log1pf(__expf(acc));
  delta[(long)m * DI + c] = sp;
}

// ---------------- selective scan + gating ----------------
// block: 256 threads = 16 n-lanes x 16 channels; grid (96, 2)
__global__ __launch_bounds__(256) void scan_kernel(
    const float* __restrict__ delta,
    const float* __restrict__ xdbl,
    const float* __restrict__ u,
    const float* __restrict__ xr,    // res = xr[m*3072 + 1536 + c]
    const float* __restrict__ A_log,
    const float* __restrict__ Dp,
    float* __restrict__ yg)
{
  const int b = blockIdx.y;
  const int c0 = blockIdx.x * 16;
  const int tid = threadIdx.x;
  const int nlane = tid & 15;
  const int chl = tid >> 4;
  const int d = c0 + chl;
  __shared__ float sDt[32][16], sU[32][16], sRes[32][16];
  __shared__ float sB[32][16], sC[32][16], sY[32][16];
  const float a = -__expf(A_log[d * NSTATE + nlane]);
  const float Dv = Dp[d];
  float h = 0.f;
  const long mbase = (long)b * LSEQ;
  for (int t0 = 0; t0 < LSEQ; t0 += 32) {
    #pragma unroll
    for (int i = 0; i < 2; ++i) {
      int idx = tid + i * 256;
      int tt = idx >> 4, ch = idx & 15;
      long m = mbase + t0 + tt;
      sDt[tt][ch] = delta[m * DI + c0 + ch];
      sU[tt][ch]  = u[m * DI + c0 + ch];
      sRes[tt][ch] = xr[m * NXR + DI + c0 + ch];
      sB[tt][ch]  = xdbl[m * 80 + DTRANK + ch];
      sC[tt][ch]  = xdbl[m * 80 + DTRANK + NSTATE + ch];
    }
    __syncthreads();
    for (int tt = 0; tt < 32; ++tt) {
      float dt = sDt[tt][chl];
      float uu = sU[tt][chl];
      float bb = sB[tt][nlane];
      float cc = sC[tt][nlane];
      float dA = __expf(dt * a);
      h = fmaf(dA, h, dt * bb * uu);
      float p = h * cc;
      p += __shfl_xor(p, 1, 16);
      p += __shfl_xor(p, 2, 16);
      p += __shfl_xor(p, 4, 16);
      p += __shfl_xor(p, 8, 16);
      if (nlane == 0) {
        float rr = sRes[tt][chl];
        float yv = p + uu * Dv;
        sY[tt][chl] = yv * rr / (1.f + __expf(-rr));
      }
    }
    __syncthreads();
    #pragma unroll
    for (int i = 0; i < 2; ++i) {
      int idx = tid + i * 256;
      int tt = idx >> 4, ch = idx & 15;
      long m = mbase + t0 + tt;
      yg[m * DI + c0 + ch] = sY[tt][ch];
    }
    __syncthreads();
  }
}

// ---------------- launch ----------------
extern "C" void kernel_launch(void* const* d_in, const int* in_sizes, int n_in,
                              void* d_out, int out_size, void* d_ws, size_t ws_size,
                              hipStream_t stream)
{
  const float* x      = (const float*)d_in[0];
  const float* W_in   = (const float*)d_in[1];
  const float* conv_w = (const float*)d_in[2];
  const float* conv_b = (const float*)d_in[3];
  const float* W_x    = (const float*)d_in[4];
  const float* W_dt   = (const float*)d_in[5];
  const float* b_dt   = (const float*)d_in[6];
  const float* A_log  = (const float*)d_in[7];
  const float* Dp     = (const float*)d_in[8];
  const float* W_out  = (const float*)d_in[9];
  float* out = (float*)d_out;

  float* ws   = (float*)d_ws;
  float* xr   = ws;                              // 2048*3072
  float* u    = xr + (size_t)MROWS * NXR;        // 2048*1536
  float* xdbl = u + (size_t)MROWS * DI;          // 2048*80
  float* delta = xdbl + (size_t)MROWS * 80;      // 2048*1536
  float* yg   = delta + (size_t)MROWS * DI;      // 2048*1536

  // 1. x @ W_in -> xr (xi | res)
  gemm_f32_64x64<<<dim3(NXR / 64, MROWS / 64), 256, 0, stream>>>(
      x, W_in, xr, MROWS, NXR, DM);
  // 2. conv + bias + silu -> u
  conv_silu_kernel<<<(MROWS * DI + 255) / 256, 256, 0, stream>>>(
      xr, conv_w, conv_b, u);
  // 3. u @ W_x -> xdbl
  xdbl_kernel<<<MROWS, 128, 0, stream>>>(u, W_x, xdbl);
  // 4. delta
  delta_kernel<<<dim3(DI / 256, MROWS), 256, 0, stream>>>(
      xdbl, W_dt, b_dt, delta);
  // 5. scan + gate -> yg
  scan_kernel<<<dim3(DI / 16, NBATCH), 256, 0, stream>>>(
      delta, xdbl, u, xr, A_log, Dp, yg);
  // 6. yg @ W_out -> out
  gemm_f32_64x64<<<dim3(DM / 64, MROWS / 64), 256, 0, stream>>>(
      yg, W_out, out, MROWS, DM, DI);
}

// Round 2
// 297.997 us; speedup vs baseline: 2.1561x; 2.1561x over previous
//
#include <hip/hip_runtime.h>
#include <math.h>

#define DI 1536
#define DM 768
#define NSTATE 16
#define DTRANK 48
#define LSEQ 1024
#define NBATCH 2
#define MROWS (NBATCH*LSEQ)   // 2048
#define NXR 3072              // 2*DI
#define NCHUNK 32
#define CLEN 32

typedef __attribute__((ext_vector_type(4))) float f32x4;
typedef __attribute__((ext_vector_type(8))) short s16x8;
typedef __attribute__((ext_vector_type(4))) unsigned int u32x4;

__device__ __forceinline__ unsigned short f2bf(float f) {
  unsigned int x = __builtin_bit_cast(unsigned int, f);
  return (unsigned short)((x + 0x7fffu + ((x >> 16) & 1u)) >> 16);
}

// ---------------- f32 -> bf16 straight convert (8 elems/thread) ----------------
__global__ __launch_bounds__(256) void convert_bf16_kernel(
    const float* __restrict__ in, unsigned short* __restrict__ out, long n)
{
  long i = ((long)blockIdx.x * 256 + threadIdx.x) * 8;
  if (i >= n) return;
  f32x4 v0 = *(const f32x4*)&in[i];
  f32x4 v1 = *(const f32x4*)&in[i + 4];
  unsigned short o[8];
  #pragma unroll
  for (int j = 0; j < 4; ++j) { o[j] = f2bf(v0[j]); o[4 + j] = f2bf(v1[j]); }
  *(u32x4*)&out[i] = *(u32x4*)o;
}

// ---------------- transpose + convert: in[R][C] f32 -> out[C][R] bf16 ----------------
__global__ __launch_bounds__(256) void transpose_bf16_kernel(
    const float* __restrict__ in, unsigned short* __restrict__ out, int R, int C)
{
  __shared__ float t[32][33];
  int ctile = blockIdx.x * 32, rtile = blockIdx.y * 32;
  int tx = threadIdx.x & 31, ty = threadIdx.x >> 5;
  #pragma unroll
  for (int i = 0; i < 4; ++i) {
    int r = ty + i * 8;
    t[r][tx] = in[(long)(rtile + r) * C + ctile + tx];
  }
  __syncthreads();
  #pragma unroll
  for (int i = 0; i < 4; ++i) {
    int cc = ty + i * 8;
    out[(long)(ctile + cc) * R + rtile + tx] = f2bf(t[tx][cc]);
  }
}

// ---------------- bf16 MFMA GEMM: C[M,N] = A[M,K] @ BT[N,K]^T ----------------
// 256 threads = 4 waves (2x2). Wave tile = 16FM x 16FN fragments of 16x16.
// LDS permuted layout: [tile16][kgroup][row16][8k] -> conflict-free b128 r/w.
template<int FM, int FN>
__global__ __launch_bounds__(256) void gemm_bf16(
    const unsigned short* __restrict__ A,
    const unsigned short* __restrict__ BT,
    float* __restrict__ C, int M, int N, int K)
{
  constexpr int BM = 32 * FM, BN = 32 * FN;
  __shared__ unsigned short Ap[BM * 32];
  __shared__ unsigned short Bp[BN * 32];
  const int tid = threadIdx.x;
  const int lane = tid & 63, wave = tid >> 6;
  const int wr = wave >> 1, wc = wave & 1;
  const int lg = lane >> 4, lr = lane & 15;
  const int m0 = blockIdx.y * BM, n0 = blockIdx.x * BN;
  f32x4 acc[FM][FN] = {};
  const int rs = tid >> 2;           // 0..63
  const int kg = tid & 3;            // k-group
  for (int k0 = 0; k0 < K; k0 += 32) {
    #pragma unroll
    for (int p = 0; p < BM / 64; ++p) {
      int r = p * 64 + rs;
      u32x4 v = *(const u32x4*)&A[(long)(m0 + r) * K + k0 + kg * 8];
      int slot = ((r >> 4) * 4 + kg) * 16 + (r & 15);
      *(u32x4*)&Ap[slot * 8] = v;
    }
    #pragma unroll
    for (int p = 0; p < BN / 64; ++p) {
      int r = p * 64 + rs;
      u32x4 v = *(const u32x4*)&BT[(long)(n0 + r) * K + k0 + kg * 8];
      int slot = ((r >> 4) * 4 + kg) * 16 + (r & 15);
      *(u32x4*)&Bp[slot * 8] = v;
    }
    __syncthreads();
    s16x8 af[FM], bfr[FN];
    #pragma unroll
    for (int m = 0; m < FM; ++m)
      af[m] = *(s16x8*)&Ap[(((wr * FM + m) * 4 + lg) * 16 + lr) * 8];
    #pragma unroll
    for (int n = 0; n < FN; ++n)
      bfr[n] = *(s16x8*)&Bp[(((wc * FN + n) * 4 + lg) * 16 + lr) * 8];
    #pragma unroll
    for (int m = 0; m < FM; ++m)
      #pragma unroll
      for (int n = 0; n < FN; ++n)
        acc[m][n] = __builtin_amdgcn_mfma_f32_16x16x32_bf16(af[m], bfr[n], acc[m][n], 0, 0, 0);
    __syncthreads();
  }
  #pragma unroll
  for (int m = 0; m < FM; ++m)
    #pragma unroll
    for (int n = 0; n < FN; ++n)
      #pragma unroll
      for (int r = 0; r < 4; ++r) {
        int row = m0 + wr * 16 * FM + m * 16 + lg * 4 + r;
        int col = n0 + wc * 16 * FN + n * 16 + lr;
        C[(long)row * N + col] = acc[m][n][r];
      }
}

// ---------------- depthwise causal conv(4) + bias + SiLU ----------------
__global__ __launch_bounds__(256) void conv_silu_kernel(
    const float* __restrict__ xr,
    const float* __restrict__ conv_w,
    const float* __restrict__ conv_b,
    float* __restrict__ u)
{
  int idx = blockIdx.x * 256 + threadIdx.x;
  if (idx >= MROWS * DI) return;
  int c = idx % DI;
  int bm = idx / DI;
  int t = bm % LSEQ;
  int b = bm / LSEQ;
  float w0 = conv_w[c * 4 + 0], w1 = conv_w[c * 4 + 1];
  float w2 = conv_w[c * 4 + 2], w3 = conv_w[c * 4 + 3];
  const float* xc = xr + (long)b * LSEQ * NXR + c;
  float acc = conv_b[c];
  if (t >= 3) acc = fmaf(xc[(long)(t - 3) * NXR], w0, acc);
  if (t >= 2) acc = fmaf(xc[(long)(t - 2) * NXR], w1, acc);
  if (t >= 1) acc = fmaf(xc[(long)(t - 1) * NXR], w2, acc);
  acc = fmaf(xc[(long)t * NXR], w3, acc);
  u[idx] = acc / (1.f + __expf(-acc));
}

// ---------------- x_dbl = u @ W_x  (2048 x 1536 @ 1536 x 80) ----------------
__global__ __launch_bounds__(128) void xdbl_kernel(
    const float* __restrict__ u,
    const float* __restrict__ W_x,
    float* __restrict__ xdbl)
{
  int m = blockIdx.x;
  int j = threadIdx.x;
  const float* ur = u + (long)m * DI;
  if (j < 80) {
    float acc = 0.f;
    #pragma unroll 4
    for (int k = 0; k < DI; ++k)
      acc = fmaf(ur[k], W_x[(long)k * 80 + j], acc);
    xdbl[(long)m * 80 + j] = acc;
  }
}

// ---------------- delta = softplus(xdbl[:, :48] @ W_dt + b_dt) ----------------
__global__ __launch_bounds__(256) void delta_kernel(
    const float* __restrict__ xdbl,
    const float* __restrict__ W_dt,
    const float* __restrict__ b_dt,
    float* __restrict__ delta)
{
  __shared__ float sx[DTRANK];
  int m = blockIdx.y;
  int c = blockIdx.x * 256 + threadIdx.x;
  if (threadIdx.x < DTRANK) sx[threadIdx.x] = xdbl[(long)m * 80 + threadIdx.x];
  __syncthreads();
  float acc = b_dt[c];
  #pragma unroll 8
  for (int r = 0; r < DTRANK; ++r)
    acc = fmaf(sx[r], W_dt[(long)r * DI + c], acc);
  float sp = (acc > 20.f) ? acc : log1pf(__expf(acc));
  delta[(long)m * DI + c] = sp;
}

// ---------------- scan phase 1: per-chunk (prod dA, h_end | h0=0) ----------------
// grid (96, 32, 2), block 256 = 16ch x 16n
__global__ __launch_bounds__(256) void scan_ph1(
    const float* __restrict__ delta,
    const float* __restrict__ xdbl,
    const float* __restrict__ u,
    const float* __restrict__ A_log,
    float* __restrict__ Aprod,
    float* __restrict__ Hend)
{
  const int b = blockIdx.z, chunk = blockIdx.y, c0 = blockIdx.x * 16;
  const int tid = threadIdx.x, nlane = tid & 15, chl = tid >> 4;
  const int d = c0 + chl;
  __shared__ float sDt[CLEN][16], sU[CLEN][16], sB[CLEN][16];
  const float a = -__expf(A_log[d * NSTATE + nlane]);
  const long mbase = (long)b * LSEQ + chunk * CLEN;
  #pragma unroll
  for (int i = 0; i < 2; ++i) {
    int idx = tid + i * 256;
    int tt = idx >> 4, ch = idx & 15;
    long m = mbase + tt;
    sDt[tt][ch] = delta[m * DI + c0 + ch];
    sU[tt][ch]  = u[m * DI + c0 + ch];
    sB[tt][ch]  = xdbl[m * 80 + DTRANK + ch];
  }
  __syncthreads();
  float h = 0.f, Ap = 1.f;
  #pragma unroll
  for (int tt = 0; tt < CLEN; ++tt) {
    float dt = sDt[tt][chl], uu = sU[tt][chl], bb = sB[tt][nlane];
    float dA = __expf(dt * a);
    Ap *= dA;
    h = fmaf(dA, h, dt * bb * uu);
  }
  long o = (((long)b * NCHUNK + chunk) * DI + d) * 16 + nlane;
  Aprod[o] = Ap;
  Hend[o] = h;
}

// ---------------- scan phase 2: propagate h across chunks ----------------
__global__ __launch_bounds__(256) void scan_ph2(
    const float* __restrict__ Aprod,
    const float* __restrict__ Hend,
    float* __restrict__ Hstart)
{
  int idx = blockIdx.x * 256 + threadIdx.x;   // [0, 2*1536*16)
  int b = idx / (DI * NSTATE);
  int r = idx % (DI * NSTATE);
  long o = (long)b * NCHUNK * DI * NSTATE + r;
  const long stride = (long)DI * NSTATE;
  float h = 0.f;
  #pragma unroll
  for (int c = 0; c < NCHUNK; ++c) {
    float Ap = Aprod[o + c * stride];
    float He = Hend[o + c * stride];
    Hstart[o + c * stride] = h;
    h = fmaf(Ap, h, He);
  }
}

// ---------------- scan phase 3: replay + y + gate -> yg (bf16) ----------------
__global__ __launch_bounds__(256) void scan_ph3(
    const float* __restrict__ delta,
    const float* __restrict__ xdbl,
    const float* __restrict__ u,
    const float* __restrict__ xr,      // res at [m*NXR + DI + c]
    const float* __restrict__ A_log,
    const float* __restrict__ Dp,
    const float* __restrict__ Hstart,
    unsigned short* __restrict__ yg)
{
  const int b = blockIdx.z, chunk = blockIdx.y, c0 = blockIdx.x * 16;
  const int tid = threadIdx.x, nlane = tid & 15, chl = tid >> 4;
  const int d = c0 + chl;
  __shared__ float sDt[CLEN][16], sU[CLEN][16], sB[CLEN][16];
  __shared__ float sC[CLEN][16], sRes[CLEN][16], sY[CLEN][16];
  const float a = -__expf(A_log[d * NSTATE + nlane]);
  const float Dv = Dp[d];
  const long mbase = (long)b * LSEQ + chunk * CLEN;
  #pragma unroll
  for (int i = 0; i < 2; ++i) {
    int idx = tid + i * 256;
    int tt = idx >> 4, ch = idx & 15;
    long m = mbase + tt;
    sDt[tt][ch]  = delta[m * DI + c0 + ch];
    sU[tt][ch]   = u[m * DI + c0 + ch];
    sRes[tt][ch] = xr[m * NXR + DI + c0 + ch];
    sB[tt][ch]   = xdbl[m * 80 + DTRANK + ch];
    sC[tt][ch]   = xdbl[m * 80 + DTRANK + NSTATE + ch];
  }
  __syncthreads();
  long o = (((long)b * NCHUNK + chunk) * DI + d) * 16 + nlane;
  float h = Hstart[o];
  for (int tt = 0; tt < CLEN; ++tt) {
    float dt = sDt[tt][chl], uu = sU[tt][chl];
    float bb = sB[tt][nlane], cc = sC[tt][nlane];
    float dA = __expf(dt * a);
    h = fmaf(dA, h, dt * bb * uu);
    float p = h * cc;
    p += __shfl_xor(p, 1, 16);
    p += __shfl_xor(p, 2, 16);
    p += __shfl_xor(p, 4, 16);
    p += __shfl_xor(p, 8, 16);
    if (nlane == 0) {
      float rr = sRes[tt][chl];
      float yv = p + uu * Dv;
      sY[tt][chl] = yv * rr / (1.f + __expf(-rr));
    }
  }
  __syncthreads();
  #pragma unroll
  for (int i = 0; i < 2; ++i) {
    int idx = tid + i * 256;
    int tt = idx >> 4, ch = idx & 15;
    long m = mbase + tt;
    yg[m * DI + c0 + ch] = f2bf(sY[tt][ch]);
  }
}

// ---------------- launch ----------------
extern "C" void kernel_launch(void* const* d_in, const int* in_sizes, int n_in,
                              void* d_out, int out_size, void* d_ws, size_t ws_size,
                              hipStream_t stream)
{
  const float* x      = (const float*)d_in[0];
  const float* W_in   = (const float*)d_in[1];
  const float* conv_w = (const float*)d_in[2];
  const float* conv_b = (const float*)d_in[3];
  const float* W_x    = (const float*)d_in[4];
  const float* W_dt   = (const float*)d_in[5];
  const float* b_dt   = (const float*)d_in[6];
  const float* A_log  = (const float*)d_in[7];
  const float* Dp     = (const float*)d_in[8];
  const float* W_out  = (const float*)d_in[9];
  float* out = (float*)d_out;

  char* p = (char*)d_ws;
  float* xr     = (float*)(p + 0);           // 25165824 B
  float* u      = (float*)(p + 25165824);    // 12582912
  float* xdbl   = (float*)(p + 37748736);    // 655360
  float* delta  = (float*)(p + 38404096);    // 12582912
  float* Aprod  = (float*)(p + 50987008);    // 6291456
  float* Hend   = (float*)(p + 57278464);    // 6291456
  unsigned short* yg    = (unsigned short*)(p + 63569920);  // 6291456
  unsigned short* WoutT = (unsigned short*)(p + 69861376);  // 2359296
  float* Hstart = (float*)(p + 72220672);    // 6291456  (total 78512128)
  // lifetime-disjoint aliases (cross-kernel only, stream-ordered):
  unsigned short* x_bf = (unsigned short*)delta;   // dead before delta written
  unsigned short* WinT = (unsigned short*)Aprod;   // dead before Aprod written

  // 0. conversions
  convert_bf16_kernel<<<(MROWS * DM) / (256 * 8), 256, 0, stream>>>(x, x_bf, (long)MROWS * DM);
  transpose_bf16_kernel<<<dim3(NXR / 32, DM / 32), 256, 0, stream>>>(W_in, WinT, DM, NXR);
  transpose_bf16_kernel<<<dim3(DM / 32, DI / 32), 256, 0, stream>>>(W_out, WoutT, DI, DM);
  // 1. x @ W_in -> xr (f32)
  gemm_bf16<4, 4><<<dim3(NXR / 128, MROWS / 128), 256, 0, stream>>>(
      x_bf, WinT, xr, MROWS, NXR, DM);
  // 2. conv + bias + silu -> u
  conv_silu_kernel<<<(MROWS * DI + 255) / 256, 256, 0, stream>>>(xr, conv_w, conv_b, u);
  // 3. u @ W_x -> xdbl
  xdbl_kernel<<<MROWS, 128, 0, stream>>>(u, W_x, xdbl);
  // 4. delta
  delta_kernel<<<dim3(DI / 256, MROWS), 256, 0, stream>>>(xdbl, W_dt, b_dt, delta);
  // 5. chunked scan
  scan_ph1<<<dim3(DI / 16, NCHUNK, NBATCH), 256, 0, stream>>>(delta, xdbl, u, A_log, Aprod, Hend);
  scan_ph2<<<(NBATCH * DI * NSTATE) / 256, 256, 0, stream>>>(Aprod, Hend, Hstart);
  scan_ph3<<<dim3(DI / 16, NCHUNK, NBATCH), 256, 0, stream>>>(
      delta, xdbl, u, xr, A_log, Dp, Hstart, yg);
  // 6. yg @ W_out -> out
  gemm_bf16<2, 2><<<dim3(DM / 64, MROWS / 64), 256, 0, stream>>>(
      yg, WoutT, out, MROWS, DM, DI);
}

// Round 3
// 207.498 us; speedup vs baseline: 3.0965x; 1.4361x over previous
//
#include <hip/hip_runtime.h>
#include <math.h>

#define DI 1536
#define DM 768
#define NSTATE 16
#define DTRANK 48
#define LSEQ 1024
#define NBATCH 2
#define MROWS (NBATCH*LSEQ)   // 2048
#define NXR 3072              // 2*DI
#define NCHUNK 32
#define CLEN 32

typedef __attribute__((ext_vector_type(4))) float f32x4;
typedef __attribute__((ext_vector_type(8))) short s16x8;
typedef __attribute__((ext_vector_type(4))) unsigned int u32x4;

__device__ __forceinline__ unsigned short f2bf(float f) {
  unsigned int x = __builtin_bit_cast(unsigned int, f);
  return (unsigned short)((x + 0x7fffu + ((x >> 16) & 1u)) >> 16);
}

// ---------------- f32 -> bf16 straight convert (8 elems/thread) ----------------
__global__ __launch_bounds__(256) void convert_bf16_kernel(
    const float* __restrict__ in, unsigned short* __restrict__ out, long n)
{
  long i = ((long)blockIdx.x * 256 + threadIdx.x) * 8;
  if (i >= n) return;
  f32x4 v0 = *(const f32x4*)&in[i];
  f32x4 v1 = *(const f32x4*)&in[i + 4];
  unsigned short o[8];
  #pragma unroll
  for (int j = 0; j < 4; ++j) { o[j] = f2bf(v0[j]); o[4 + j] = f2bf(v1[j]); }
  *(u32x4*)&out[i] = *(u32x4*)o;
}

// ---------------- transpose + convert: in[R][C] f32 -> out[C][R] bf16 ----------------
__global__ __launch_bounds__(256) void transpose_bf16_kernel(
    const float* __restrict__ in, unsigned short* __restrict__ out, int R, int C)
{
  __shared__ float t[32][33];
  int ctile = blockIdx.x * 32, rtile = blockIdx.y * 32;
  int tx = threadIdx.x & 31, ty = threadIdx.x >> 5;
  #pragma unroll
  for (int i = 0; i < 4; ++i) {
    int r = ty + i * 8;
    t[r][tx] = in[(long)(rtile + r) * C + ctile + tx];
  }
  __syncthreads();
  #pragma unroll
  for (int i = 0; i < 4; ++i) {
    int cc = ty + i * 8;
    out[(long)(ctile + cc) * R + rtile + tx] = f2bf(t[tx][cc]);
  }
}

// ---------------- guarded transpose (R,C arbitrary): in[R][C] -> out[C][R] bf16 ----------------
__global__ __launch_bounds__(256) void transpose_bf16_guard(
    const float* __restrict__ in, unsigned short* __restrict__ out, int R, int C)
{
  __shared__ float t[32][33];
  int ctile = blockIdx.x * 32, rtile = blockIdx.y * 32;
  int tx = threadIdx.x & 31, ty = threadIdx.x >> 5;
  #pragma unroll
  for (int i = 0; i < 4; ++i) {
    int r = ty + i * 8;
    if (rtile + r < R && ctile + tx < C)
      t[r][tx] = in[(long)(rtile + r) * C + ctile + tx];
  }
  __syncthreads();
  #pragma unroll
  for (int i = 0; i < 4; ++i) {
    int cc = ty + i * 8;
    if (ctile + cc < C && rtile + tx < R)
      out[(long)(ctile + cc) * R + rtile + tx] = f2bf(t[tx][cc]);
  }
}

// ---------------- bf16 MFMA GEMM: C[M,N] = A[M,K] @ BT[N,K]^T ----------------
template<int FM, int FN>
__global__ __launch_bounds__(256) void gemm_bf16(
    const unsigned short* __restrict__ A,
    const unsigned short* __restrict__ BT,
    float* __restrict__ C, int M, int N, int K)
{
  constexpr int BM = 32 * FM, BN = 32 * FN;
  __shared__ unsigned short Ap[BM * 32];
  __shared__ unsigned short Bp[BN * 32];
  const int tid = threadIdx.x;
  const int lane = tid & 63, wave = tid >> 6;
  const int wr = wave >> 1, wc = wave & 1;
  const int lg = lane >> 4, lr = lane & 15;
  const int m0 = blockIdx.y * BM, n0 = blockIdx.x * BN;
  f32x4 acc[FM][FN] = {};
  const int rs = tid >> 2;           // 0..63
  const int kg = tid & 3;            // k-group
  for (int k0 = 0; k0 < K; k0 += 32) {
    #pragma unroll
    for (int p = 0; p < BM / 64; ++p) {
      int r = p * 64 + rs;
      u32x4 v = *(const u32x4*)&A[(long)(m0 + r) * K + k0 + kg * 8];
      int slot = ((r >> 4) * 4 + kg) * 16 + (r & 15);
      *(u32x4*)&Ap[slot * 8] = v;
    }
    #pragma unroll
    for (int p = 0; p < BN / 64; ++p) {
      int r = p * 64 + rs;
      u32x4 v = *(const u32x4*)&BT[(long)(n0 + r) * K + k0 + kg * 8];
      int slot = ((r >> 4) * 4 + kg) * 16 + (r & 15);
      *(u32x4*)&Bp[slot * 8] = v;
    }
    __syncthreads();
    s16x8 af[FM], bfr[FN];
    #pragma unroll
    for (int m = 0; m < FM; ++m)
      af[m] = *(s16x8*)&Ap[(((wr * FM + m) * 4 + lg) * 16 + lr) * 8];
    #pragma unroll
    for (int n = 0; n < FN; ++n)
      bfr[n] = *(s16x8*)&Bp[(((wc * FN + n) * 4 + lg) * 16 + lr) * 8];
    #pragma unroll
    for (int m = 0; m < FM; ++m)
      #pragma unroll
      for (int n = 0; n < FN; ++n)
        acc[m][n] = __builtin_amdgcn_mfma_f32_16x16x32_bf16(af[m], bfr[n], acc[m][n], 0, 0, 0);
    __syncthreads();
  }
  #pragma unroll
  for (int m = 0; m < FM; ++m)
    #pragma unroll
    for (int n = 0; n < FN; ++n)
      #pragma unroll
      for (int r = 0; r < 4; ++r) {
        int row = m0 + wr * 16 * FM + m * 16 + lg * 4 + r;
        int col = n0 + wc * 16 * FN + n * 16 + lr;
        C[(long)row * N + col] = acc[m][n][r];
      }
}

// ---------------- depthwise causal conv(4) + bias + SiLU (f32 + bf16 out) ----------------
__global__ __launch_bounds__(256) void conv_silu_kernel(
    const float* __restrict__ xr,
    const float* __restrict__ conv_w,
    const float* __restrict__ conv_b,
    float* __restrict__ u,
    unsigned short* __restrict__ u_bf)
{
  int idx = blockIdx.x * 256 + threadIdx.x;
  if (idx >= MROWS * DI) return;
  int c = idx % DI;
  int bm = idx / DI;
  int t = bm % LSEQ;
  int b = bm / LSEQ;
  float w0 = conv_w[c * 4 + 0], w1 = conv_w[c * 4 + 1];
  float w2 = conv_w[c * 4 + 2], w3 = conv_w[c * 4 + 3];
  const float* xc = xr + (long)b * LSEQ * NXR + c;
  float acc = conv_b[c];
  if (t >= 3) acc = fmaf(xc[(long)(t - 3) * NXR], w0, acc);
  if (t >= 2) acc = fmaf(xc[(long)(t - 2) * NXR], w1, acc);
  if (t >= 1) acc = fmaf(xc[(long)(t - 1) * NXR], w2, acc);
  acc = fmaf(xc[(long)t * NXR], w3, acc);
  float s = acc / (1.f + __expf(-acc));
  u[idx] = s;
  u_bf[idx] = f2bf(s);
}

// ---------------- x_dbl = u @ W_x via MFMA; BM=16, 4 waves split K ----------------
// grid: MROWS/16 = 128 blocks, 256 threads. WxT is [80][1536] bf16.
__global__ __launch_bounds__(256) void xdbl_mfma(
    const unsigned short* __restrict__ u_bf,
    const unsigned short* __restrict__ WxT,
    float* __restrict__ xdbl)
{
  const int tid = threadIdx.x;
  const int lane = tid & 63, wave = tid >> 6;
  const int lg = lane >> 4, lr = lane & 15;
  const int m0 = blockIdx.x * 16;
  f32x4 acc[5] = {};
  const int kbase = wave * (DI / 4);   // 384 per wave
  #pragma unroll
  for (int kk = 0; kk < DI / 4; kk += 32) {
    int k0 = kbase + kk;
    s16x8 af = *(const s16x8*)&u_bf[(long)(m0 + lr) * DI + k0 + lg * 8];
    #pragma unroll
    for (int n = 0; n < 5; ++n) {
      s16x8 bfr = *(const s16x8*)&WxT[(long)(n * 16 + lr) * DI + k0 + lg * 8];
      acc[n] = __builtin_amdgcn_mfma_f32_16x16x32_bf16(af, bfr, acc[n], 0, 0, 0);
    }
  }
  __shared__ float red[4][16][80];
  #pragma unroll
  for (int n = 0; n < 5; ++n)
    #pragma unroll
    for (int r = 0; r < 4; ++r)
      red[wave][lg * 4 + r][n * 16 + lr] = acc[n][r];
  __syncthreads();
  for (int i = tid; i < 16 * 80; i += 256) {
    int row = i / 80, col = i % 80;
    float s = red[0][row][col] + red[1][row][col] + red[2][row][col] + red[3][row][col];
    xdbl[(long)(m0 + row) * 80 + col] = s;
  }
}

// ---------------- delta = softplus(xdbl[:, :48] @ W_dt + b_dt) ----------------
__global__ __launch_bounds__(256) void delta_kernel(
    const float* __restrict__ xdbl,
    const float* __restrict__ W_dt,
    const float* __restrict__ b_dt,
    float* __restrict__ delta)
{
  __shared__ float sx[DTRANK];
  int m = blockIdx.y;
  int c = blockIdx.x * 256 + threadIdx.x;
  if (threadIdx.x < DTRANK) sx[threadIdx.x] = xdbl[(long)m * 80 + threadIdx.x];
  __syncthreads();
  float acc = b_dt[c];
  #pragma unroll 8
  for (int r = 0; r < DTRANK; ++r)
    acc = fmaf(sx[r], W_dt[(long)r * DI + c], acc);
  float sp = (acc > 20.f) ? acc : log1pf(__expf(acc));
  delta[(long)m * DI + c] = sp;
}

// ---------------- scan phase 1: per-chunk (prod dA, h_end | h0=0) ----------------
__global__ __launch_bounds__(256) void scan_ph1(
    const float* __restrict__ delta,
    const float* __restrict__ xdbl,
    const float* __restrict__ u,
    const float* __restrict__ A_log,
    float* __restrict__ Aprod,
    float* __restrict__ Hend)
{
  const int b = blockIdx.z, chunk = blockIdx.y, c0 = blockIdx.x * 16;
  const int tid = threadIdx.x, nlane = tid & 15, chl = tid >> 4;
  const int d = c0 + chl;
  __shared__ float sDt[CLEN][16], sU[CLEN][16], sB[CLEN][16];
  const float a = -__expf(A_log[d * NSTATE + nlane]);
  const long mbase = (long)b * LSEQ + chunk * CLEN;
  #pragma unroll
  for (int i = 0; i < 2; ++i) {
    int idx = tid + i * 256;
    int tt = idx >> 4, ch = idx & 15;
    long m = mbase + tt;
    sDt[tt][ch] = delta[m * DI + c0 + ch];
    sU[tt][ch]  = u[m * DI + c0 + ch];
    sB[tt][ch]  = xdbl[m * 80 + DTRANK + ch];
  }
  __syncthreads();
  float h = 0.f, Ap = 1.f;
  #pragma unroll
  for (int tt = 0; tt < CLEN; ++tt) {
    float dt = sDt[tt][chl], uu = sU[tt][chl], bb = sB[tt][nlane];
    float dA = __expf(dt * a);
    Ap *= dA;
    h = fmaf(dA, h, dt * bb * uu);
  }
  long o = (((long)b * NCHUNK + chunk) * DI + d) * 16 + nlane;
  Aprod[o] = Ap;
  Hend[o] = h;
}

// ---------------- scan phase 2: propagate h across chunks ----------------
__global__ __launch_bounds__(256) void scan_ph2(
    const float* __restrict__ Aprod,
    const float* __restrict__ Hend,
    float* __restrict__ Hstart)
{
  int idx = blockIdx.x * 256 + threadIdx.x;   // [0, 2*1536*16)
  int b = idx / (DI * NSTATE);
  int r = idx % (DI * NSTATE);
  long o = (long)b * NCHUNK * DI * NSTATE + r;
  const long stride = (long)DI * NSTATE;
  float h = 0.f;
  #pragma unroll
  for (int c = 0; c < NCHUNK; ++c) {
    float Ap = Aprod[o + c * stride];
    float He = Hend[o + c * stride];
    Hstart[o + c * stride] = h;
    h = fmaf(Ap, h, He);
  }
}

// ---------------- scan phase 3: replay + y + gate -> yg (bf16) ----------------
__global__ __launch_bounds__(256) void scan_ph3(
    const float* __restrict__ delta,
    const float* __restrict__ xdbl,
    const float* __restrict__ u,
    const float* __restrict__ xr,      // res at [m*NXR + DI + c]
    const float* __restrict__ A_log,
    const float* __restrict__ Dp,
    const float* __restrict__ Hstart,
    unsigned short* __restrict__ yg)
{
  const int b = blockIdx.z, chunk = blockIdx.y, c0 = blockIdx.x * 16;
  const int tid = threadIdx.x, nlane = tid & 15, chl = tid >> 4;
  const int d = c0 + chl;
  __shared__ float sDt[CLEN][16], sU[CLEN][16], sB[CLEN][16];
  __shared__ float sC[CLEN][16], sRes[CLEN][16], sY[CLEN][16];
  const float a = -__expf(A_log[d * NSTATE + nlane]);
  const float Dv = Dp[d];
  const long mbase = (long)b * LSEQ + chunk * CLEN;
  #pragma unroll
  for (int i = 0; i < 2; ++i) {
    int idx = tid + i * 256;
    int tt = idx >> 4, ch = idx & 15;
    long m = mbase + tt;
    sDt[tt][ch]  = delta[m * DI + c0 + ch];
    sU[tt][ch]   = u[m * DI + c0 + ch];
    sRes[tt][ch] = xr[m * NXR + DI + c0 + ch];
    sB[tt][ch]   = xdbl[m * 80 + DTRANK + ch];
    sC[tt][ch]   = xdbl[m * 80 + DTRANK + NSTATE + ch];
  }
  __syncthreads();
  long o = (((long)b * NCHUNK + chunk) * DI + d) * 16 + nlane;
  float h = Hstart[o];
  for (int tt = 0; tt < CLEN; ++tt) {
    float dt = sDt[tt][chl], uu = sU[tt][chl];
    float bb = sB[tt][nlane], cc = sC[tt][nlane];
    float dA = __expf(dt * a);
    h = fmaf(dA, h, dt * bb * uu);
    float p = h * cc;
    p += __shfl_xor(p, 1, 16);
    p += __shfl_xor(p, 2, 16);
    p += __shfl_xor(p, 4, 16);
    p += __shfl_xor(p, 8, 16);
    if (nlane == 0) {
      float rr = sRes[tt][chl];
      float yv = p + uu * Dv;
      sY[tt][chl] = yv * rr / (1.f + __expf(-rr));
    }
  }
  __syncthreads();
  #pragma unroll
  for (int i = 0; i < 2; ++i) {
    int idx = tid + i * 256;
    int tt = idx >> 4, ch = idx & 15;
    long m = mbase + tt;
    yg[m * DI + c0 + ch] = f2bf(sY[tt][ch]);
  }
}

// ---------------- launch ----------------
extern "C" void kernel_launch(void* const* d_in, const int* in_sizes, int n_in,
                              void* d_out, int out_size, void* d_ws, size_t ws_size,
                              hipStream_t stream)
{
  const float* x      = (const float*)d_in[0];
  const float* W_in   = (const float*)d_in[1];
  const float* conv_w = (const float*)d_in[2];
  const float* conv_b = (const float*)d_in[3];
  const float* W_x    = (const float*)d_in[4];
  const float* W_dt   = (const float*)d_in[5];
  const float* b_dt   = (const float*)d_in[6];
  const float* A_log  = (const float*)d_in[7];
  const float* Dp     = (const float*)d_in[8];
  const float* W_out  = (const float*)d_in[9];
  float* out = (float*)d_out;

  char* p = (char*)d_ws;
  float* xr     = (float*)(p + 0);           // 25165824 B
  float* u      = (float*)(p + 25165824);    // 12582912
  float* xdbl   = (float*)(p + 37748736);    // 655360
  float* delta  = (float*)(p + 38404096);    // 12582912
  float* Aprod  = (float*)(p + 50987008);    // 6291456
  float* Hend   = (float*)(p + 57278464);    // 6291456
  unsigned short* yg    = (unsigned short*)(p + 63569920);  // 6291456
  unsigned short* WoutT = (unsigned short*)(p + 69861376);  // 2359296
  float* Hstart = (float*)(p + 72220672);    // 6291456  (total 78512128)
  // lifetime-disjoint aliases (cross-kernel only, stream-ordered):
  unsigned short* x_bf = (unsigned short*)delta;    // dead before delta written
  unsigned short* WinT = (unsigned short*)Aprod;    // dead before Aprod written (ph1)
  unsigned short* u_bf = (unsigned short*)Hend;     // consumed by xdbl_mfma, before Hend written (ph1)
  unsigned short* WxT  = (unsigned short*)Hstart;   // consumed by xdbl_mfma, before Hstart written (ph2)

  // 0. conversions
  convert_bf16_kernel<<<(MROWS * DM) / (256 * 8), 256, 0, stream>>>(x, x_bf, (long)MROWS * DM);
  transpose_bf16_kernel<<<dim3(NXR / 32, DM / 32), 256, 0, stream>>>(W_in, WinT, DM, NXR);
  transpose_bf16_kernel<<<dim3(DM / 32, DI / 32), 256, 0, stream>>>(W_out, WoutT, DI, DM);
  transpose_bf16_guard<<<dim3(3, DI / 32), 256, 0, stream>>>(W_x, WxT, DI, 80);
  // 1. x @ W_in -> xr (f32)
  gemm_bf16<4, 4><<<dim3(NXR / 128, MROWS / 128), 256, 0, stream>>>(
      x_bf, WinT, xr, MROWS, NXR, DM);
  // 2. conv + bias + silu -> u (f32) + u_bf (bf16)
  conv_silu_kernel<<<(MROWS * DI + 255) / 256, 256, 0, stream>>>(xr, conv_w, conv_b, u, u_bf);
  // 3. u @ W_x -> xdbl (MFMA, K split across 4 waves)
  xdbl_mfma<<<MROWS / 16, 256, 0, stream>>>(u_bf, WxT, xdbl);
  // 4. delta
  delta_kernel<<<dim3(DI / 256, MROWS), 256, 0, stream>>>(xdbl, W_dt, b_dt, delta);
  // 5. chunked scan
  scan_ph1<<<dim3(DI / 16, NCHUNK, NBATCH), 256, 0, stream>>>(delta, xdbl, u, A_log, Aprod, Hend);
  scan_ph2<<<(NBATCH * DI * NSTATE) / 256, 256, 0, stream>>>(Aprod, Hend, Hstart);
  scan_ph3<<<dim3(DI / 16, NCHUNK, NBATCH), 256, 0, stream>>>(
      delta, xdbl, u, xr, A_log, Dp, Hstart, yg);
  // 6. yg @ W_out -> out
  gemm_bf16<2, 2><<<dim3(DM / 64, MROWS / 64), 256, 0, stream>>>(
      yg, WoutT, out, MROWS, DM, DI);
}

// Round 4
// 191.691 us; speedup vs baseline: 3.3518x; 1.0825x over previous
//
#include <hip/hip_runtime.h>
#include <math.h>

#define DI 1536
#define DM 768
#define NSTATE 16
#define DTRANK 48
#define LSEQ 1024
#define NBATCH 2
#define MROWS (NBATCH*LSEQ)   // 2048
#define NXR 3072              // 2*DI
#define NCHUNK 32
#define CLEN 32
#define SCB 128               // scan channels per block

typedef __attribute__((ext_vector_type(4))) float f32x4;
typedef __attribute__((ext_vector_type(8))) short s16x8;
typedef __attribute__((ext_vector_type(4))) unsigned int u32x4;

__device__ __forceinline__ unsigned short f2bf(float f) {
  unsigned int x = __builtin_bit_cast(unsigned int, f);
  return (unsigned short)((x + 0x7fffu + ((x >> 16) & 1u)) >> 16);
}

// ---------------- f32 -> bf16 straight convert (8 elems/thread) ----------------
__global__ __launch_bounds__(256) void convert_bf16_kernel(
    const float* __restrict__ in, unsigned short* __restrict__ out, long n)
{
  long i = ((long)blockIdx.x * 256 + threadIdx.x) * 8;
  if (i >= n) return;
  f32x4 v0 = *(const f32x4*)&in[i];
  f32x4 v1 = *(const f32x4*)&in[i + 4];
  unsigned short o[8];
  #pragma unroll
  for (int j = 0; j < 4; ++j) { o[j] = f2bf(v0[j]); o[4 + j] = f2bf(v1[j]); }
  *(u32x4*)&out[i] = *(u32x4*)o;
}

// ---------------- transpose + convert: in[R][C] f32 -> out[C][R] bf16 ----------------
__global__ __launch_bounds__(256) void transpose_bf16_kernel(
    const float* __restrict__ in, unsigned short* __restrict__ out, int R, int C)
{
  __shared__ float t[32][33];
  int ctile = blockIdx.x * 32, rtile = blockIdx.y * 32;
  int tx = threadIdx.x & 31, ty = threadIdx.x >> 5;
  #pragma unroll
  for (int i = 0; i < 4; ++i) {
    int r = ty + i * 8;
    t[r][tx] = in[(long)(rtile + r) * C + ctile + tx];
  }
  __syncthreads();
  #pragma unroll
  for (int i = 0; i < 4; ++i) {
    int cc = ty + i * 8;
    out[(long)(ctile + cc) * R + rtile + tx] = f2bf(t[tx][cc]);
  }
}

// ---------------- guarded transpose (R,C arbitrary): in[R][C] -> out[C][R] bf16 ----------------
__global__ __launch_bounds__(256) void transpose_bf16_guard(
    const float* __restrict__ in, unsigned short* __restrict__ out, int R, int C)
{
  __shared__ float t[32][33];
  int ctile = blockIdx.x * 32, rtile = blockIdx.y * 32;
  int tx = threadIdx.x & 31, ty = threadIdx.x >> 5;
  #pragma unroll
  for (int i = 0; i < 4; ++i) {
    int r = ty + i * 8;
    if (rtile + r < R && ctile + tx < C)
      t[r][tx] = in[(long)(rtile + r) * C + ctile + tx];
  }
  __syncthreads();
  #pragma unroll
  for (int i = 0; i < 4; ++i) {
    int cc = ty + i * 8;
    if (ctile + cc < C && rtile + tx < R)
      out[(long)(ctile + cc) * R + rtile + tx] = f2bf(t[tx][cc]);
  }
}

// ---------------- bf16 MFMA GEMM: C[M,N] = A[M,K] @ BT[N,K]^T ----------------
template<int FM, int FN>
__global__ __launch_bounds__(256) void gemm_bf16(
    const unsigned short* __restrict__ A,
    const unsigned short* __restrict__ BT,
    float* __restrict__ C, int M, int N, int K)
{
  constexpr int BM = 32 * FM, BN = 32 * FN;
  __shared__ unsigned short Ap[BM * 32];
  __shared__ unsigned short Bp[BN * 32];
  const int tid = threadIdx.x;
  const int lane = tid & 63, wave = tid >> 6;
  const int wr = wave >> 1, wc = wave & 1;
  const int lg = lane >> 4, lr = lane & 15;
  const int m0 = blockIdx.y * BM, n0 = blockIdx.x * BN;
  f32x4 acc[FM][FN] = {};
  const int rs = tid >> 2;           // 0..63
  const int kg = tid & 3;            // k-group
  for (int k0 = 0; k0 < K; k0 += 32) {
    #pragma unroll
    for (int p = 0; p < BM / 64; ++p) {
      int r = p * 64 + rs;
      u32x4 v = *(const u32x4*)&A[(long)(m0 + r) * K + k0 + kg * 8];
      int slot = ((r >> 4) * 4 + kg) * 16 + (r & 15);
      *(u32x4*)&Ap[slot * 8] = v;
    }
    #pragma unroll
    for (int p = 0; p < BN / 64; ++p) {
      int r = p * 64 + rs;
      u32x4 v = *(const u32x4*)&BT[(long)(n0 + r) * K + k0 + kg * 8];
      int slot = ((r >> 4) * 4 + kg) * 16 + (r & 15);
      *(u32x4*)&Bp[slot * 8] = v;
    }
    __syncthreads();
    s16x8 af[FM], bfr[FN];
    #pragma unroll
    for (int m = 0; m < FM; ++m)
      af[m] = *(s16x8*)&Ap[(((wr * FM + m) * 4 + lg) * 16 + lr) * 8];
    #pragma unroll
    for (int n = 0; n < FN; ++n)
      bfr[n] = *(s16x8*)&Bp[(((wc * FN + n) * 4 + lg) * 16 + lr) * 8];
    #pragma unroll
    for (int m = 0; m < FM; ++m)
      #pragma unroll
      for (int n = 0; n < FN; ++n)
        acc[m][n] = __builtin_amdgcn_mfma_f32_16x16x32_bf16(af[m], bfr[n], acc[m][n], 0, 0, 0);
    __syncthreads();
  }
  #pragma unroll
  for (int m = 0; m < FM; ++m)
    #pragma unroll
    for (int n = 0; n < FN; ++n)
      #pragma unroll
      for (int r = 0; r < 4; ++r) {
        int row = m0 + wr * 16 * FM + m * 16 + lg * 4 + r;
        int col = n0 + wc * 16 * FN + n * 16 + lr;
        C[(long)row * N + col] = acc[m][n][r];
      }
}

// ---------------- depthwise causal conv(4) + bias + SiLU (f32 + bf16 out) ----------------
__global__ __launch_bounds__(256) void conv_silu_kernel(
    const float* __restrict__ xr,
    const float* __restrict__ conv_w,
    const float* __restrict__ conv_b,
    float* __restrict__ u,
    unsigned short* __restrict__ u_bf)
{
  int idx = blockIdx.x * 256 + threadIdx.x;
  if (idx >= MROWS * DI) return;
  int c = idx % DI;
  int bm = idx / DI;
  int t = bm % LSEQ;
  int b = bm / LSEQ;
  float w0 = conv_w[c * 4 + 0], w1 = conv_w[c * 4 + 1];
  float w2 = conv_w[c * 4 + 2], w3 = conv_w[c * 4 + 3];
  const float* xc = xr + (long)b * LSEQ * NXR + c;
  float acc = conv_b[c];
  if (t >= 3) acc = fmaf(xc[(long)(t - 3) * NXR], w0, acc);
  if (t >= 2) acc = fmaf(xc[(long)(t - 2) * NXR], w1, acc);
  if (t >= 1) acc = fmaf(xc[(long)(t - 1) * NXR], w2, acc);
  acc = fmaf(xc[(long)t * NXR], w3, acc);
  float s = acc / (1.f + __expf(-acc));
  u[idx] = s;
  u_bf[idx] = f2bf(s);
}

// ---------------- x_dbl = u @ W_x via MFMA; BM=16, 4 waves split K ----------------
__global__ __launch_bounds__(256) void xdbl_mfma(
    const unsigned short* __restrict__ u_bf,
    const unsigned short* __restrict__ WxT,
    float* __restrict__ xdbl)
{
  const int tid = threadIdx.x;
  const int lane = tid & 63, wave = tid >> 6;
  const int lg = lane >> 4, lr = lane & 15;
  const int m0 = blockIdx.x * 16;
  f32x4 acc[5] = {};
  const int kbase = wave * (DI / 4);   // 384 per wave
  #pragma unroll
  for (int kk = 0; kk < DI / 4; kk += 32) {
    int k0 = kbase + kk;
    s16x8 af = *(const s16x8*)&u_bf[(long)(m0 + lr) * DI + k0 + lg * 8];
    #pragma unroll
    for (int n = 0; n < 5; ++n) {
      s16x8 bfr = *(const s16x8*)&WxT[(long)(n * 16 + lr) * DI + k0 + lg * 8];
      acc[n] = __builtin_amdgcn_mfma_f32_16x16x32_bf16(af, bfr, acc[n], 0, 0, 0);
    }
  }
  __shared__ float red[4][16][80];
  #pragma unroll
  for (int n = 0; n < 5; ++n)
    #pragma unroll
    for (int r = 0; r < 4; ++r)
      red[wave][lg * 4 + r][n * 16 + lr] = acc[n][r];
  __syncthreads();
  for (int i = tid; i < 16 * 80; i += 256) {
    int row = i / 80, col = i % 80;
    float s = red[0][row][col] + red[1][row][col] + red[2][row][col] + red[3][row][col];
    xdbl[(long)(m0 + row) * 80 + col] = s;
  }
}

// ---------------- delta = softplus(xdbl[:, :48] @ W_dt + b_dt) ----------------
__global__ __launch_bounds__(256) void delta_kernel(
    const float* __restrict__ xdbl,
    const float* __restrict__ W_dt,
    const float* __restrict__ b_dt,
    float* __restrict__ delta)
{
  __shared__ float sx[DTRANK];
  int m = blockIdx.y;
  int c = blockIdx.x * 256 + threadIdx.x;
  if (threadIdx.x < DTRANK) sx[threadIdx.x] = xdbl[(long)m * 80 + threadIdx.x];
  __syncthreads();
  float acc = b_dt[c];
  #pragma unroll 8
  for (int r = 0; r < DTRANK; ++r)
    acc = fmaf(sx[r], W_dt[(long)r * DI + c], acc);
  float sp = (acc > 20.f) ? acc : log1pf(__expf(acc));
  delta[(long)m * DI + c] = sp;
}

// ---------------- scan phase 1: thread-per-channel, 16 states in registers ----------------
// grid (DI/SCB=12, NCHUNK, NBATCH), block SCB=128
__global__ __launch_bounds__(SCB) void scan_ph1(
    const float* __restrict__ delta,
    const float* __restrict__ xdbl,
    const float* __restrict__ u,
    const float* __restrict__ A_log,
    float* __restrict__ Aprod,
    float* __restrict__ Hend)
{
  const int b = blockIdx.z, chunk = blockIdx.y;
  const int tid = threadIdx.x;
  const int d = blockIdx.x * SCB + tid;
  const long mbase = (long)b * LSEQ + chunk * CLEN;
  __shared__ float sB[CLEN][NSTATE];
  for (int i = tid; i < CLEN * NSTATE; i += SCB) {
    int t = i >> 4, j = i & 15;
    sB[t][j] = xdbl[(mbase + t) * 80 + DTRANK + j];
  }
  __syncthreads();
  float a[NSTATE];
  #pragma unroll
  for (int n = 0; n < NSTATE; ++n)
    a[n] = -__expf(A_log[(long)d * NSTATE + n]);
  float h[NSTATE] = {};
  float Ap[NSTATE];
  #pragma unroll
  for (int n = 0; n < NSTATE; ++n) Ap[n] = 1.f;
  #pragma unroll 4
  for (int t = 0; t < CLEN; ++t) {
    long m = mbase + t;
    float dt = delta[m * DI + d];
    float uu = u[m * DI + d];
    float dtu = dt * uu;
    #pragma unroll
    for (int n = 0; n < NSTATE; ++n) {
      float dA = __expf(dt * a[n]);
      Ap[n] *= dA;
      h[n] = fmaf(dA, h[n], dtu * sB[t][n]);
    }
  }
  long o = (((long)b * NCHUNK + chunk) * DI + d) * NSTATE;
  #pragma unroll
  for (int q = 0; q < 4; ++q) {
    f32x4 va = { Ap[q*4+0], Ap[q*4+1], Ap[q*4+2], Ap[q*4+3] };
    f32x4 vh = { h[q*4+0], h[q*4+1], h[q*4+2], h[q*4+3] };
    *(f32x4*)&Aprod[o + q*4] = va;
    *(f32x4*)&Hend[o + q*4] = vh;
  }
}

// ---------------- scan phase 2: propagate h across chunks ----------------
__global__ __launch_bounds__(256) void scan_ph2(
    const float* __restrict__ Aprod,
    const float* __restrict__ Hend,
    float* __restrict__ Hstart)
{
  int idx = blockIdx.x * 256 + threadIdx.x;   // [0, 2*1536*16)
  int b = idx / (DI * NSTATE);
  int r = idx % (DI * NSTATE);
  long o = (long)b * NCHUNK * DI * NSTATE + r;
  const long stride = (long)DI * NSTATE;
  float h = 0.f;
  #pragma unroll
  for (int c = 0; c < NCHUNK; ++c) {
    float Ap = Aprod[o + c * stride];
    float He = Hend[o + c * stride];
    Hstart[o + c * stride] = h;
    h = fmaf(Ap, h, He);
  }
}

// ---------------- scan phase 3: replay + y + gate -> yg (bf16) ----------------
__global__ __launch_bounds__(SCB) void scan_ph3(
    const float* __restrict__ delta,
    const float* __restrict__ xdbl,
    const float* __restrict__ u,
    const float* __restrict__ xr,      // res at [m*NXR + DI + d]
    const float* __restrict__ A_log,
    const float* __restrict__ Dp,
    const float* __restrict__ Hstart,
    unsigned short* __restrict__ yg)
{
  const int b = blockIdx.z, chunk = blockIdx.y;
  const int tid = threadIdx.x;
  const int d = blockIdx.x * SCB + tid;
  const long mbase = (long)b * LSEQ + chunk * CLEN;
  __shared__ float sB[CLEN][NSTATE], sC[CLEN][NSTATE];
  for (int i = tid; i < CLEN * NSTATE; i += SCB) {
    int t = i >> 4, j = i & 15;
    long mo = (mbase + t) * 80 + DTRANK + j;
    sB[t][j] = xdbl[mo];
    sC[t][j] = xdbl[mo + NSTATE];
  }
  __syncthreads();
  float a[NSTATE];
  #pragma unroll
  for (int n = 0; n < NSTATE; ++n)
    a[n] = -__expf(A_log[(long)d * NSTATE + n]);
  const float Dv = Dp[d];
  long o = (((long)b * NCHUNK + chunk) * DI + d) * NSTATE;
  float h[NSTATE];
  #pragma unroll
  for (int q = 0; q < 4; ++q) {
    f32x4 vh = *(const f32x4*)&Hstart[o + q*4];
    h[q*4+0] = vh[0]; h[q*4+1] = vh[1]; h[q*4+2] = vh[2]; h[q*4+3] = vh[3];
  }
  #pragma unroll 4
  for (int t = 0; t < CLEN; ++t) {
    long m = mbase + t;
    float dt = delta[m * DI + d];
    float uu = u[m * DI + d];
    float rr = xr[m * NXR + DI + d];
    float dtu = dt * uu;
    float p0 = 0.f, p1 = 0.f, p2 = 0.f, p3 = 0.f;
    #pragma unroll
    for (int q = 0; q < 4; ++q) {
      float dA0 = __expf(dt * a[q*4+0]);
      float dA1 = __expf(dt * a[q*4+1]);
      float dA2 = __expf(dt * a[q*4+2]);
      float dA3 = __expf(dt * a[q*4+3]);
      h[q*4+0] = fmaf(dA0, h[q*4+0], dtu * sB[t][q*4+0]);
      h[q*4+1] = fmaf(dA1, h[q*4+1], dtu * sB[t][q*4+1]);
      h[q*4+2] = fmaf(dA2, h[q*4+2], dtu * sB[t][q*4+2]);
      h[q*4+3] = fmaf(dA3, h[q*4+3], dtu * sB[t][q*4+3]);
    }
    #pragma unroll
    for (int n = 0; n < NSTATE; n += 4) {
      p0 = fmaf(h[n+0], sC[t][n+0], p0);
      p1 = fmaf(h[n+1], sC[t][n+1], p1);
      p2 = fmaf(h[n+2], sC[t][n+2], p2);
      p3 = fmaf(h[n+3], sC[t][n+3], p3);
    }
    float yv = (p0 + p1) + (p2 + p3) + uu * Dv;
    float gate = rr / (1.f + __expf(-rr));
    yg[m * DI + d] = f2bf(yv * gate);
  }
}

// ---------------- launch ----------------
extern "C" void kernel_launch(void* const* d_in, const int* in_sizes, int n_in,
                              void* d_out, int out_size, void* d_ws, size_t ws_size,
                              hipStream_t stream)
{
  const float* x      = (const float*)d_in[0];
  const float* W_in   = (const float*)d_in[1];
  const float* conv_w = (const float*)d_in[2];
  const float* conv_b = (const float*)d_in[3];
  const float* W_x    = (const float*)d_in[4];
  const float* W_dt   = (const float*)d_in[5];
  const float* b_dt   = (const float*)d_in[6];
  const float* A_log  = (const float*)d_in[7];
  const float* Dp     = (const float*)d_in[8];
  const float* W_out  = (const float*)d_in[9];
  float* out = (float*)d_out;

  char* p = (char*)d_ws;
  float* xr     = (float*)(p + 0);           // 25165824 B
  float* u      = (float*)(p + 25165824);    // 12582912
  float* xdbl   = (float*)(p + 37748736);    // 655360
  float* delta  = (float*)(p + 38404096);    // 12582912
  float* Aprod  = (float*)(p + 50987008);    // 6291456
  float* Hend   = (float*)(p + 57278464);    // 6291456
  unsigned short* yg    = (unsigned short*)(p + 63569920);  // 6291456
  unsigned short* WoutT = (unsigned short*)(p + 69861376);  // 2359296
  float* Hstart = (float*)(p + 72220672);    // 6291456  (total 78512128)
  // lifetime-disjoint aliases (cross-kernel only, stream-ordered):
  unsigned short* x_bf = (unsigned short*)delta;    // dead before delta written
  unsigned short* WinT = (unsigned short*)Aprod;    // dead before Aprod written (ph1)
  unsigned short* u_bf = (unsigned short*)Hend;     // consumed by xdbl_mfma, before Hend written (ph1)
  unsigned short* WxT  = (unsigned short*)Hstart;   // consumed by xdbl_mfma, before Hstart written (ph2)

  // 0. conversions
  convert_bf16_kernel<<<(MROWS * DM) / (256 * 8), 256, 0, stream>>>(x, x_bf, (long)MROWS * DM);
  transpose_bf16_kernel<<<dim3(NXR / 32, DM / 32), 256, 0, stream>>>(W_in, WinT, DM, NXR);
  transpose_bf16_kernel<<<dim3(DM / 32, DI / 32), 256, 0, stream>>>(W_out, WoutT, DI, DM);
  transpose_bf16_guard<<<dim3(3, DI / 32), 256, 0, stream>>>(W_x, WxT, DI, 80);
  // 1. x @ W_in -> xr (f32)
  gemm_bf16<4, 4><<<dim3(NXR / 128, MROWS / 128), 256, 0, stream>>>(
      x_bf, WinT, xr, MROWS, NXR, DM);
  // 2. conv + bias + silu -> u (f32) + u_bf (bf16)
  conv_silu_kernel<<<(MROWS * DI + 255) / 256, 256, 0, stream>>>(xr, conv_w, conv_b, u, u_bf);
  // 3. u @ W_x -> xdbl (MFMA, K split across 4 waves)
  xdbl_mfma<<<MROWS / 16, 256, 0, stream>>>(u_bf, WxT, xdbl);
  // 4. delta
  delta_kernel<<<dim3(DI / 256, MROWS), 256, 0, stream>>>(xdbl, W_dt, b_dt, delta);
  // 5. chunked scan (thread-per-channel register form)
  scan_ph1<<<dim3(DI / SCB, NCHUNK, NBATCH), SCB, 0, stream>>>(delta, xdbl, u, A_log, Aprod, Hend);
  scan_ph2<<<(NBATCH * DI * NSTATE) / 256, 256, 0, stream>>>(Aprod, Hend, Hstart);
  scan_ph3<<<dim3(DI / SCB, NCHUNK, NBATCH), SCB, 0, stream>>>(
      delta, xdbl, u, xr, A_log, Dp, Hstart, yg);
  // 6. yg @ W_out -> out
  gemm_bf16<2, 2><<<dim3(DM / 64, MROWS / 64), 256, 0, stream>>>(
      yg, WoutT, out, MROWS, DM, DI);
}

// Round 5
// 176.211 us; speedup vs baseline: 3.6463x; 1.0878x over previous
//
#include <hip/hip_runtime.h>
#include <math.h>

#define DI 1536
#define DM 768
#define NSTATE 16
#define DTRANK 48
#define LSEQ 1024
#define NBATCH 2
#define MROWS (NBATCH*LSEQ)   // 2048
#define NXR 3072              // 2*DI
#define NCHUNK 64
#define CLEN 16
#define SCB 128               // scan channels per block
#define DMP 16                // delta rows per block

typedef __attribute__((ext_vector_type(4))) float f32x4;
typedef __attribute__((ext_vector_type(8))) short s16x8;
typedef __attribute__((ext_vector_type(4))) unsigned int u32x4;

__device__ __forceinline__ unsigned short f2bf(float f) {
  unsigned int x = __builtin_bit_cast(unsigned int, f);
  return (unsigned short)((x + 0x7fffu + ((x >> 16) & 1u)) >> 16);
}

__device__ __forceinline__ void gload_lds16(const void* g, void* l) {
  __builtin_amdgcn_global_load_lds(
      (const __attribute__((address_space(1))) void*)g,
      (__attribute__((address_space(3))) void*)l, 16, 0, 0);
}

// ---------------- f32 -> bf16 straight convert (8 elems/thread) ----------------
__global__ __launch_bounds__(256) void convert_bf16_kernel(
    const float* __restrict__ in, unsigned short* __restrict__ out, long n)
{
  long i = ((long)blockIdx.x * 256 + threadIdx.x) * 8;
  if (i >= n) return;
  f32x4 v0 = *(const f32x4*)&in[i];
  f32x4 v1 = *(const f32x4*)&in[i + 4];
  unsigned short o[8];
  #pragma unroll
  for (int j = 0; j < 4; ++j) { o[j] = f2bf(v0[j]); o[4 + j] = f2bf(v1[j]); }
  *(u32x4*)&out[i] = *(u32x4*)o;
}

// ---------------- transpose + convert: in[R][C] f32 -> out[C][R] bf16 ----------------
__global__ __launch_bounds__(256) void transpose_bf16_kernel(
    const float* __restrict__ in, unsigned short* __restrict__ out, int R, int C)
{
  __shared__ float t[32][33];
  int ctile = blockIdx.x * 32, rtile = blockIdx.y * 32;
  int tx = threadIdx.x & 31, ty = threadIdx.x >> 5;
  #pragma unroll
  for (int i = 0; i < 4; ++i) {
    int r = ty + i * 8;
    t[r][tx] = in[(long)(rtile + r) * C + ctile + tx];
  }
  __syncthreads();
  #pragma unroll
  for (int i = 0; i < 4; ++i) {
    int cc = ty + i * 8;
    out[(long)(ctile + cc) * R + rtile + tx] = f2bf(t[tx][cc]);
  }
}

// ---------------- guarded transpose (R,C arbitrary): in[R][C] -> out[C][R] bf16 ----------------
__global__ __launch_bounds__(256) void transpose_bf16_guard(
    const float* __restrict__ in, unsigned short* __restrict__ out, int R, int C)
{
  __shared__ float t[32][33];
  int ctile = blockIdx.x * 32, rtile = blockIdx.y * 32;
  int tx = threadIdx.x & 31, ty = threadIdx.x >> 5;
  #pragma unroll
  for (int i = 0; i < 4; ++i) {
    int r = ty + i * 8;
    if (rtile + r < R && ctile + tx < C)
      t[r][tx] = in[(long)(rtile + r) * C + ctile + tx];
  }
  __syncthreads();
  #pragma unroll
  for (int i = 0; i < 4; ++i) {
    int cc = ty + i * 8;
    if (ctile + cc < C && rtile + tx < R)
      out[(long)(ctile + cc) * R + rtile + tx] = f2bf(t[tx][cc]);
  }
}

// ---------------- bf16 MFMA GEMM: C[M,N] = A[M,K] @ BT[N,K]^T ----------------
// global_load_lds(16B) staging. LDS layout: [tile16][kg][row16][8k], and
// per-wave linear landing (lane = kg*16+row) matches it exactly.
template<int FM, int FN>
__global__ __launch_bounds__(256) void gemm_bf16(
    const unsigned short* __restrict__ A,
    const unsigned short* __restrict__ BT,
    float* __restrict__ C, int M, int N, int K)
{
  constexpr int BM = 32 * FM, BN = 32 * FN;
  constexpr int TM = BM / 16, TN = BN / 16;   // #16-row tiles
  __shared__ unsigned short Ap[BM * 32];
  __shared__ unsigned short Bp[BN * 32];
  const int tid = threadIdx.x;
  const int lane = tid & 63, wave = tid >> 6;
  const int wr = wave >> 1, wc = wave & 1;
  const int lg = lane >> 4, lr = lane & 15;   // staging: kg = lg, row = lr
  const int m0 = blockIdx.y * BM, n0 = blockIdx.x * BN;
  f32x4 acc[FM][FN] = {};
  for (int k0 = 0; k0 < K; k0 += 32) {
    #pragma unroll
    for (int p = 0; p < TM / 4; ++p) {
      int tile = wave + p * 4;
      gload_lds16(&A[(long)(m0 + tile * 16 + lr) * K + k0 + lg * 8],
                  &Ap[tile * 512]);
    }
    #pragma unroll
    for (int p = 0; p < TN / 4; ++p) {
      int tile = wave + p * 4;
      gload_lds16(&BT[(long)(n0 + tile * 16 + lr) * K + k0 + lg * 8],
                  &Bp[tile * 512]);
    }
    __syncthreads();
    s16x8 af[FM], bfr[FN];
    #pragma unroll
    for (int m = 0; m < FM; ++m)
      af[m] = *(s16x8*)&Ap[(((wr * FM + m) * 4 + lg) * 16 + lr) * 8];
    #pragma unroll
    for (int n = 0; n < FN; ++n)
      bfr[n] = *(s16x8*)&Bp[(((wc * FN + n) * 4 + lg) * 16 + lr) * 8];
    #pragma unroll
    for (int m = 0; m < FM; ++m)
      #pragma unroll
      for (int n = 0; n < FN; ++n)
        acc[m][n] = __builtin_amdgcn_mfma_f32_16x16x32_bf16(af[m], bfr[n], acc[m][n], 0, 0, 0);
    __syncthreads();
  }
  #pragma unroll
  for (int m = 0; m < FM; ++m)
    #pragma unroll
    for (int n = 0; n < FN; ++n)
      #pragma unroll
      for (int r = 0; r < 4; ++r) {
        int row = m0 + wr * 16 * FM + m * 16 + lg * 4 + r;
        int col = n0 + wc * 16 * FN + n * 16 + lr;
        C[(long)row * N + col] = acc[m][n][r];
      }
}

// ---------------- depthwise causal conv(4) + bias + SiLU (f32 + bf16 out) ----------------
__global__ __launch_bounds__(256) void conv_silu_kernel(
    const float* __restrict__ xr,
    const float* __restrict__ conv_w,
    const float* __restrict__ conv_b,
    float* __restrict__ u,
    unsigned short* __restrict__ u_bf)
{
  int idx = blockIdx.x * 256 + threadIdx.x;
  if (idx >= MROWS * DI) return;
  int c = idx % DI;
  int bm = idx / DI;
  int t = bm % LSEQ;
  int b = bm / LSEQ;
  float w0 = conv_w[c * 4 + 0], w1 = conv_w[c * 4 + 1];
  float w2 = conv_w[c * 4 + 2], w3 = conv_w[c * 4 + 3];
  const float* xc = xr + (long)b * LSEQ * NXR + c;
  float acc = conv_b[c];
  if (t >= 3) acc = fmaf(xc[(long)(t - 3) * NXR], w0, acc);
  if (t >= 2) acc = fmaf(xc[(long)(t - 2) * NXR], w1, acc);
  if (t >= 1) acc = fmaf(xc[(long)(t - 1) * NXR], w2, acc);
  acc = fmaf(xc[(long)t * NXR], w3, acc);
  float s = acc / (1.f + __expf(-acc));
  u[idx] = s;
  u_bf[idx] = f2bf(s);
}

// ---------------- x_dbl = u @ W_x via MFMA; BM=16, 4 waves split K ----------------
__global__ __launch_bounds__(256) void xdbl_mfma(
    const unsigned short* __restrict__ u_bf,
    const unsigned short* __restrict__ WxT,
    float* __restrict__ xdbl)
{
  const int tid = threadIdx.x;
  const int lane = tid & 63, wave = tid >> 6;
  const int lg = lane >> 4, lr = lane & 15;
  const int m0 = blockIdx.x * 16;
  f32x4 acc[5] = {};
  const int kbase = wave * (DI / 4);   // 384 per wave
  #pragma unroll
  for (int kk = 0; kk < DI / 4; kk += 32) {
    int k0 = kbase + kk;
    s16x8 af = *(const s16x8*)&u_bf[(long)(m0 + lr) * DI + k0 + lg * 8];
    #pragma unroll
    for (int n = 0; n < 5; ++n) {
      s16x8 bfr = *(const s16x8*)&WxT[(long)(n * 16 + lr) * DI + k0 + lg * 8];
      acc[n] = __builtin_amdgcn_mfma_f32_16x16x32_bf16(af, bfr, acc[n], 0, 0, 0);
    }
  }
  __shared__ float red[4][16][80];
  #pragma unroll
  for (int n = 0; n < 5; ++n)
    #pragma unroll
    for (int r = 0; r < 4; ++r)
      red[wave][lg * 4 + r][n * 16 + lr] = acc[n][r];
  __syncthreads();
  for (int i = tid; i < 16 * 80; i += 256) {
    int row = i / 80, col = i % 80;
    float s = red[0][row][col] + red[1][row][col] + red[2][row][col] + red[3][row][col];
    xdbl[(long)(m0 + row) * 80 + col] = s;
  }
}

// ---------------- delta = softplus(xdbl[:, :48] @ W_dt + b_dt) ----------------
// 16 m-rows per block; W_dt element read once per 16 rows (L2 traffic /16).
__global__ __launch_bounds__(256) void delta_kernel(
    const float* __restrict__ xdbl,
    const float* __restrict__ W_dt,
    const float* __restrict__ b_dt,
    float* __restrict__ delta)
{
  __shared__ float sx[DMP][DTRANK];
  const int tid = threadIdx.x;
  const int c = blockIdx.x * 256 + tid;
  const int m0 = blockIdx.y * DMP;
  for (int i = tid; i < DMP * DTRANK; i += 256) {
    int mm = i / DTRANK, r = i % DTRANK;
    sx[mm][r] = xdbl[(long)(m0 + mm) * 80 + r];
  }
  __syncthreads();
  float bias = b_dt[c];
  float acc[DMP];
  #pragma unroll
  for (int mm = 0; mm < DMP; ++mm) acc[mm] = bias;
  for (int r = 0; r < DTRANK; ++r) {
    float wv = W_dt[(long)r * DI + c];
    #pragma unroll
    for (int mm = 0; mm < DMP; ++mm)
      acc[mm] = fmaf(sx[mm][r], wv, acc[mm]);
  }
  #pragma unroll
  for (int mm = 0; mm < DMP; ++mm) {
    float v = acc[mm];
    float sp = (v > 20.f) ? v : log1pf(__expf(v));
    delta[(long)(m0 + mm) * DI + c] = sp;
  }
}

// ---------------- scan phase 1: thread-per-channel, 16 states in registers ----------------
// grid (DI/SCB=12, NCHUNK, NBATCH), block SCB=128
__global__ __launch_bounds__(SCB) void scan_ph1(
    const float* __restrict__ delta,
    const float* __restrict__ xdbl,
    const float* __restrict__ u,
    const float* __restrict__ A_log,
    float* __restrict__ Aprod,
    float* __restrict__ Hend)
{
  const int b = blockIdx.z, chunk = blockIdx.y;
  const int tid = threadIdx.x;
  const int d = blockIdx.x * SCB + tid;
  const long mbase = (long)b * LSEQ + chunk * CLEN;
  __shared__ float sB[CLEN][NSTATE];
  for (int i = tid; i < CLEN * NSTATE; i += SCB) {
    int t = i >> 4, j = i & 15;
    sB[t][j] = xdbl[(mbase + t) * 80 + DTRANK + j];
  }
  __syncthreads();
  float a[NSTATE];
  #pragma unroll
  for (int n = 0; n < NSTATE; ++n)
    a[n] = -__expf(A_log[(long)d * NSTATE + n]);
  float h[NSTATE] = {};
  float Ap[NSTATE];
  #pragma unroll
  for (int n = 0; n < NSTATE; ++n) Ap[n] = 1.f;
  #pragma unroll 4
  for (int t = 0; t < CLEN; ++t) {
    long m = mbase + t;
    float dt = delta[m * DI + d];
    float uu = u[m * DI + d];
    float dtu = dt * uu;
    #pragma unroll
    for (int n = 0; n < NSTATE; ++n) {
      float dA = __expf(dt * a[n]);
      Ap[n] *= dA;
      h[n] = fmaf(dA, h[n], dtu * sB[t][n]);
    }
  }
  long o = (((long)b * NCHUNK + chunk) * DI + d) * NSTATE;
  #pragma unroll
  for (int q = 0; q < 4; ++q) {
    f32x4 va = { Ap[q*4+0], Ap[q*4+1], Ap[q*4+2], Ap[q*4+3] };
    f32x4 vh = { h[q*4+0], h[q*4+1], h[q*4+2], h[q*4+3] };
    *(f32x4*)&Aprod[o + q*4] = va;
    *(f32x4*)&Hend[o + q*4] = vh;
  }
}

// ---------------- scan phase 2: propagate h across chunks ----------------
__global__ __launch_bounds__(256) void scan_ph2(
    const float* __restrict__ Aprod,
    const float* __restrict__ Hend,
    float* __restrict__ Hstart)
{
  int idx = blockIdx.x * 256 + threadIdx.x;   // [0, 2*1536*16)
  int b = idx / (DI * NSTATE);
  int r = idx % (DI * NSTATE);
  long o = (long)b * NCHUNK * DI * NSTATE + r;
  const long stride = (long)DI * NSTATE;
  float h = 0.f;
  for (int c = 0; c < NCHUNK; ++c) {
    float Ap = Aprod[o + c * stride];
    float He = Hend[o + c * stride];
    Hstart[o + c * stride] = h;
    h = fmaf(Ap, h, He);
  }
}

// ---------------- scan phase 3: replay + y + gate -> yg (bf16) ----------------
__global__ __launch_bounds__(SCB) void scan_ph3(
    const float* __restrict__ delta,
    const float* __restrict__ xdbl,
    const float* __restrict__ u,
    const float* __restrict__ xr,      // res at [m*NXR + DI + d]
    const float* __restrict__ A_log,
    const float* __restrict__ Dp,
    const float* __restrict__ Hstart,
    unsigned short* __restrict__ yg)
{
  const int b = blockIdx.z, chunk = blockIdx.y;
  const int tid = threadIdx.x;
  const int d = blockIdx.x * SCB + tid;
  const long mbase = (long)b * LSEQ + chunk * CLEN;
  __shared__ float sB[CLEN][NSTATE], sC[CLEN][NSTATE];
  for (int i = tid; i < CLEN * NSTATE; i += SCB) {
    int t = i >> 4, j = i & 15;
    long mo = (mbase + t) * 80 + DTRANK + j;
    sB[t][j] = xdbl[mo];
    sC[t][j] = xdbl[mo + NSTATE];
  }
  __syncthreads();
  float a[NSTATE];
  #pragma unroll
  for (int n = 0; n < NSTATE; ++n)
    a[n] = -__expf(A_log[(long)d * NSTATE + n]);
  const float Dv = Dp[d];
  long o = (((long)b * NCHUNK + chunk) * DI + d) * NSTATE;
  float h[NSTATE];
  #pragma unroll
  for (int q = 0; q < 4; ++q) {
    f32x4 vh = *(const f32x4*)&Hstart[o + q*4];
    h[q*4+0] = vh[0]; h[q*4+1] = vh[1]; h[q*4+2] = vh[2]; h[q*4+3] = vh[3];
  }
  #pragma unroll 4
  for (int t = 0; t < CLEN; ++t) {
    long m = mbase + t;
    float dt = delta[m * DI + d];
    float uu = u[m * DI + d];
    float rr = xr[m * NXR + DI + d];
    float dtu = dt * uu;
    float p0 = 0.f, p1 = 0.f, p2 = 0.f, p3 = 0.f;
    #pragma unroll
    for (int q = 0; q < 4; ++q) {
      float dA0 = __expf(dt * a[q*4+0]);
      float dA1 = __expf(dt * a[q*4+1]);
      float dA2 = __expf(dt * a[q*4+2]);
      float dA3 = __expf(dt * a[q*4+3]);
      h[q*4+0] = fmaf(dA0, h[q*4+0], dtu * sB[t][q*4+0]);
      h[q*4+1] = fmaf(dA1, h[q*4+1], dtu * sB[t][q*4+1]);
      h[q*4+2] = fmaf(dA2, h[q*4+2], dtu * sB[t][q*4+2]);
      h[q*4+3] = fmaf(dA3, h[q*4+3], dtu * sB[t][q*4+3]);
    }
    #pragma unroll
    for (int n = 0; n < NSTATE; n += 4) {
      p0 = fmaf(h[n+0], sC[t][n+0], p0);
      p1 = fmaf(h[n+1], sC[t][n+1], p1);
      p2 = fmaf(h[n+2], sC[t][n+2], p2);
      p3 = fmaf(h[n+3], sC[t][n+3], p3);
    }
    float yv = (p0 + p1) + (p2 + p3) + uu * Dv;
    float gate = rr / (1.f + __expf(-rr));
    yg[m * DI + d] = f2bf(yv * gate);
  }
}

// ---------------- launch ----------------
extern "C" void kernel_launch(void* const* d_in, const int* in_sizes, int n_in,
                              void* d_out, int out_size, void* d_ws, size_t ws_size,
                              hipStream_t stream)
{
  const float* x      = (const float*)d_in[0];
  const float* W_in   = (const float*)d_in[1];
  const float* conv_w = (const float*)d_in[2];
  const float* conv_b = (const float*)d_in[3];
  const float* W_x    = (const float*)d_in[4];
  const float* W_dt   = (const float*)d_in[5];
  const float* b_dt   = (const float*)d_in[6];
  const float* A_log  = (const float*)d_in[7];
  const float* Dp     = (const float*)d_in[8];
  const float* W_out  = (const float*)d_in[9];
  float* out = (float*)d_out;

  char* p = (char*)d_ws;
  float* xr     = (float*)(p + 0);           // 25165824 B
  float* u      = (float*)(p + 25165824);    // 12582912
  float* xdbl   = (float*)(p + 37748736);    // 655360
  float* delta  = (float*)(p + 38404096);    // 12582912
  float* Aprod  = (float*)(p + 50987008);    // 12582912 (NCHUNK=64)
  float* Hend   = (float*)(p + 63569920);    // 12582912
  unsigned short* yg    = (unsigned short*)(p + 76152832);  // 6291456
  unsigned short* WoutT = (unsigned short*)(p + 82444288);  // 2359296
  float* Hstart = (float*)(p + 84803584);    // 12582912  (total 97386496)
  // lifetime-disjoint aliases (cross-kernel only, stream-ordered):
  unsigned short* x_bf = (unsigned short*)delta;    // dead before delta written
  unsigned short* WinT = (unsigned short*)Aprod;    // dead before Aprod written (ph1)
  unsigned short* u_bf = (unsigned short*)Hend;     // consumed by xdbl_mfma, before Hend written (ph1)
  unsigned short* WxT  = (unsigned short*)Hstart;   // consumed by xdbl_mfma, before Hstart written (ph2)

  // 0. conversions
  convert_bf16_kernel<<<(MROWS * DM) / (256 * 8), 256, 0, stream>>>(x, x_bf, (long)MROWS * DM);
  transpose_bf16_kernel<<<dim3(NXR / 32, DM / 32), 256, 0, stream>>>(W_in, WinT, DM, NXR);
  transpose_bf16_kernel<<<dim3(DM / 32, DI / 32), 256, 0, stream>>>(W_out, WoutT, DI, DM);
  transpose_bf16_guard<<<dim3(3, DI / 32), 256, 0, stream>>>(W_x, WxT, DI, 80);
  // 1. x @ W_in -> xr (f32)
  gemm_bf16<4, 4><<<dim3(NXR / 128, MROWS / 128), 256, 0, stream>>>(
      x_bf, WinT, xr, MROWS, NXR, DM);
  // 2. conv + bias + silu -> u (f32) + u_bf (bf16)
  conv_silu_kernel<<<(MROWS * DI + 255) / 256, 256, 0, stream>>>(xr, conv_w, conv_b, u, u_bf);
  // 3. u @ W_x -> xdbl (MFMA, K split across 4 waves)
  xdbl_mfma<<<MROWS / 16, 256, 0, stream>>>(u_bf, WxT, xdbl);
  // 4. delta
  delta_kernel<<<dim3(DI / 256, MROWS / DMP), 256, 0, stream>>>(xdbl, W_dt, b_dt, delta);
  // 5. chunked scan (thread-per-channel register form)
  scan_ph1<<<dim3(DI / SCB, NCHUNK, NBATCH), SCB, 0, stream>>>(delta, xdbl, u, A_log, Aprod, Hend);
  scan_ph2<<<(NBATCH * DI * NSTATE) / 256, 256, 0, stream>>>(Aprod, Hend, Hstart);
  scan_ph3<<<dim3(DI / SCB, NCHUNK, NBATCH), SCB, 0, stream>>>(
      delta, xdbl, u, xr, A_log, Dp, Hstart, yg);
  // 6. yg @ W_out -> out
  gemm_bf16<2, 2><<<dim3(DM / 64, MROWS / 64), 256, 0, stream>>>(
      yg, WoutT, out, MROWS, DM, DI);
}